// Round 8
// baseline (26.742 us; speedup 1.0000x reference)
//
#include <hip/hip_runtime.h>

// B=2, N=512, C_IN=16, C_OUT=16, HID=64
#define NQ   512
#define CI   16
#define CO   16
#define HIDN 64

typedef __attribute__((ext_vector_type(8))) short bf16x8;
typedef __attribute__((ext_vector_type(4))) float f32x4;

// packed bf16 convert: low16 = bf16(a), high16 = bf16(b)
__device__ __forceinline__ unsigned cvt_pk_bf16(float a, float b) {
    unsigned r;
    asm("v_cvt_pk_bf16_f32 %0, %1, %2" : "=v"(r) : "v"(a), "v"(b));
    return r;
}

// ---------------------------------------------------------------------------
// 2048 blocks (2 per zb), 256 threads = 4 waves; each wave owns 64 'a'.
//
//   M[i][h] = sum_j f[j]*W2[(i*16+j)*64+h]   (f32 in LDS, padded rows)
//   c[i]    = sum_j f[j]*b2[i*16+j]
//   out[a,b,i] = sum_h gelu(W1·[rel,|rel|]+b1)[a,h] * M[i][h] + c[i]
//
// MFMA with SWAPPED operands: D^T = M_bf16(hi/lo) · hv^T. A-frag = M rows
// (m=i=lane&15), B-frag = hv (n=a=lane&15) — same per-lane data as the
// round-5 unswapped version, but D has i in the reg index -> contiguous
// dwordx4 stores. C folded into accumulator init (c[g*4+r]).
// ---------------------------------------------------------------------------
__global__ __launch_bounds__(256, 4) void fused_mfma_kernel(
    const float* __restrict__ features,   // [1024,16]
    const float* __restrict__ geometry,   // [1024,3]
    const float* __restrict__ W1,         // [64,4]
    const float* __restrict__ b1,         // [64]
    const float* __restrict__ W2,         // [256,64]
    const float* __restrict__ b2,         // [256]
    float* __restrict__ out)              // [2,512,512,16]
{
    __shared__ __attribute__((aligned(16))) float M_sm[CO][68]; // 272B rows, 16B-aligned
    __shared__ float c_sm[CO];
    __shared__ float f_sm[CI];

    const int bid = blockIdx.x;
    const int zb  = bid >> 1;            // z*512 + b
    const int a0  = (bid & 1) << 8;
    const int z   = zb >> 9;
    const int b   = zb & 511;
    const int tid = threadIdx.x;

    if (tid < CI) f_sm[tid] = features[zb * CI + tid];
    __syncthreads();

    const int wv   = tid >> 6;
    const int lane = tid & 63;
    const int col  = lane & 15;          // = i for A-frag, = a for B-frag
    const int g    = lane >> 4;
    const int abase = a0 + wv * 64;

    // ---- geometry / rel early (independent of stage A) ----
    const float gbx = geometry[(z * NQ + b) * 3 + 0];
    const float gby = geometry[(z * NQ + b) * 3 + 1];
    const float gbz = geometry[(z * NQ + b) * 3 + 2];
    float rel[4][4];
    #pragma unroll
    for (int t = 0; t < 4; ++t) {
        const float* ga = geometry + (size_t)(z * NQ + abase + t * 16 + col) * 3;
        float rx = gbx - ga[0], ry = gby - ga[1], rz = gbz - ga[2];
        rel[t][0] = rx; rel[t][1] = ry; rel[t][2] = rz;
        rel[t][3] = sqrtf(fmaf(rx, rx, fmaf(ry, ry, rz * rz)) + 1e-12f);
    }

    // ---- stage A: M into LDS. Each thread: 4 consecutive k of one i ----
    {
        const int i  = tid >> 4;         // 0..15
        const int k4 = (tid & 15) * 4;   // 0..60
        float4 acc = {0.f, 0.f, 0.f, 0.f};
        #pragma unroll
        for (int j = 0; j < CI; ++j) {
            const float fj = f_sm[j];
            const float4 w2 = *reinterpret_cast<const float4*>(&W2[(i * CI + j) * HIDN + k4]);
            acc.x = fmaf(fj, w2.x, acc.x);
            acc.y = fmaf(fj, w2.y, acc.y);
            acc.z = fmaf(fj, w2.z, acc.z);
            acc.w = fmaf(fj, w2.w, acc.w);
        }
        *reinterpret_cast<float4*>(&M_sm[i][k4]) = acc;   // 16B-aligned (aligned(16) + 272B rows)
    }
    if (tid < CO) {
        float acc = 0.f;
        #pragma unroll
        for (int j = 0; j < CI; ++j)
            acc = fmaf(f_sm[j], b2[tid * CI + j], acc);
        c_sm[tid] = acc;
    }
    __syncthreads();

    // ---- A fragments: hi/lo bf16 split of M (m = i = col), scalar LDS reads ----
    bf16x8 Af[2][2];   // [part][kc]
    #pragma unroll
    for (int kc = 0; kc < 2; ++kc) {
        const float* mp = &M_sm[col][kc * 32 + g * 8];
        unsigned hpk[4], lpk[4];
        #pragma unroll
        for (int p = 0; p < 4; ++p) {
            float m0 = mp[2 * p], m1 = mp[2 * p + 1];
            unsigned h = cvt_pk_bf16(m0, m1);
            float h0 = __builtin_bit_cast(float, h << 16);
            float h1 = __builtin_bit_cast(float, h & 0xffff0000u);
            hpk[p] = h;
            lpk[p] = cvt_pk_bf16(m0 - h0, m1 - h1);
        }
        union { unsigned u[4]; bf16x8 v; } uh, ul;
        #pragma unroll
        for (int p = 0; p < 4; ++p) { uh.u[p] = hpk[p]; ul.u[p] = lpk[p]; }
        Af[0][kc] = uh.v;
        Af[1][kc] = ul.v;
    }

    // ---- accumulator init: lane (col,g) holds D^T rows i = g*4+r, col a = col ----
    f32x4 cin;
    #pragma unroll
    for (int r = 0; r < 4; ++r) cin[r] = c_sm[g * 4 + r];   // scalar LDS reads
    f32x4 acc[4];
    #pragma unroll
    for (int t = 0; t < 4; ++t) acc[t] = cin;

    // ---- main: hv (B-frag: n=a=col, k=g*8+j), 2 MFMAs (hi+lo) per (t,kc) ----
    #pragma unroll
    for (int kc = 0; kc < 2; ++kc) {
        float4 w[8]; float bb[8];
        #pragma unroll
        for (int j = 0; j < 8; ++j) {
            int h = kc * 32 + g * 8 + j;
            w[j]  = *reinterpret_cast<const float4*>(W1 + h * 4);
            bb[j] = b1[h];
        }
        #pragma unroll
        for (int t = 0; t < 4; ++t) {
            float hv[8];
            #pragma unroll
            for (int j = 0; j < 8; ++j) {
                float x = bb[j];
                x = fmaf(rel[t][0], w[j].x, x);
                x = fmaf(rel[t][1], w[j].y, x);
                x = fmaf(rel[t][2], w[j].z, x);
                x = fmaf(rel[t][3], w[j].w, x);
                // gelu (tanh approx, sigmoid form)
                float q = fmaf(x * x, 0.044715f, 1.0f);
                float e = __builtin_amdgcn_exp2f((-2.3022082f * x) * q);
                hv[j]   = x * __builtin_amdgcn_rcpf(1.0f + e);
            }
            union { unsigned u[4]; bf16x8 v; } ua;
            #pragma unroll
            for (int p = 0; p < 4; ++p)
                ua.u[p] = cvt_pk_bf16(hv[2 * p], hv[2 * p + 1]);
            acc[t] = __builtin_amdgcn_mfma_f32_16x16x32_bf16(Af[0][kc], ua.v, acc[t], 0, 0, 0);
            acc[t] = __builtin_amdgcn_mfma_f32_16x16x32_bf16(Af[1][kc], ua.v, acc[t], 0, 0, 0);
        }
    }

    // ---- epilogue: row a = abase+t*16+col, cols i = g*4..g*4+3 -> dwordx4 ----
    #pragma unroll
    for (int t = 0; t < 4; ++t) {
        float* op = out + (((size_t)(z * NQ + abase + t * 16 + col)) * NQ + b) * CO + g * 4;
        *reinterpret_cast<f32x4*>(op) = acc[t];
    }
}

extern "C" void kernel_launch(void* const* d_in, const int* in_sizes, int n_in,
                              void* d_out, int out_size, void* d_ws, size_t ws_size,
                              hipStream_t stream) {
    const float* features = (const float*)d_in[0];
    const float* geometry = (const float*)d_in[1];
    const float* W1       = (const float*)d_in[2];
    const float* b1       = (const float*)d_in[3];
    const float* W2       = (const float*)d_in[4];
    const float* b2       = (const float*)d_in[5];
    float* out = (float*)d_out;

    fused_mfma_kernel<<<2048, 256, 0, stream>>>(
        features, geometry, W1, b1, W2, b2, out);
}